// Round 16
// baseline (2347.716 us; speedup 1.0000x reference)
//
#include <hip/hip_runtime.h>
#include <hip/hip_bf16.h>

#define B_ 128
#define T_ 256
#define TA_ 8
#define E_ 512
#define H_ 512
#define D_ 1024
#define G3_ 1536

typedef __attribute__((ext_vector_type(8))) short bf16x8_;
typedef __attribute__((ext_vector_type(4))) float f32x4_;

__device__ __forceinline__ float sigmoidf_(float x) { return 1.0f / (1.0f + __expf(-x)); }

__device__ __forceinline__ unsigned short f2bf_(float f) {
  unsigned u = __float_as_uint(f);
  return (unsigned short)((u + 0x7FFFu + ((u >> 16) & 1u)) >> 16);   // RNE
}
__device__ __forceinline__ float bf2f_(unsigned short b) {
  return __uint_as_float((unsigned)b << 16);
}

// ---- transpose w_hh (512 x 1536) -> w_hhT (1536 x 512) -------------------
__global__ __launch_bounds__(256) void k_transpose(const float* __restrict__ w, float* __restrict__ wt) {
  __shared__ float tile[32][33];
  const int tx = threadIdx.x & 31, ty = threadIdx.x >> 5;
  const int c0 = blockIdx.x * 32, i0 = blockIdx.y * 32;
#pragma unroll
  for (int r = 0; r < 4; ++r) {
    int ii = ty + r * 8;
    tile[ii][tx] = w[(size_t)(i0 + ii) * G3_ + c0 + tx];
  }
  __syncthreads();
#pragma unroll
  for (int r = 0; r < 4; ++r) {
    int cc = ty + r * 8;
    wt[(size_t)(c0 + cc) * H_ + i0 + tx] = tile[tx][cc];
  }
}

// ---- pre-split w_ih[E:2E] -> bf16 hi/lo, transposed to [col][k] ------------
__global__ __launch_bounds__(256) void k_prep_bsplit(const float* __restrict__ w_ih,
                                                     unsigned short* __restrict__ Bhg,
                                                     unsigned short* __restrict__ Blg) {
  __shared__ float tile[32][33];
  const int tx = threadIdx.x & 31, ty = threadIdx.x >> 5;
  const int g0 = blockIdx.x * 32, kk0 = blockIdx.y * 32;
#pragma unroll
  for (int r = 0; r < 4; ++r) {
    int kl = ty + r * 8;
    tile[kl][tx] = w_ih[(size_t)(E_ + kk0 + kl) * G3_ + g0 + tx];
  }
  __syncthreads();
#pragma unroll
  for (int r = 0; r < 4; ++r) {
    const int gl = ty + r * 8;
    const float f = tile[tx][gl];            // w[kk0+tx][g0+gl]
    const unsigned short hb = f2bf_(f);
    Bhg[(size_t)(g0 + gl) * E_ + kk0 + tx] = hb;
    Blg[(size_t)(g0 + gl) * E_ + kk0 + tx] = f2bf_(f - bf2f_(hb));
  }
}

// ---- aspect mean pooling --------------------------------------------------
__global__ __launch_bounds__(256) void k_asp_pool(const int* __restrict__ aidx, const float* __restrict__ embed,
                                                  float* __restrict__ ap) {
  const int b = blockIdx.x;
  int ai[TA_]; int cnt = 0;
#pragma unroll
  for (int ta = 0; ta < TA_; ++ta) { ai[ta] = aidx[b * TA_ + ta]; cnt += (ai[ta] != 0); }
  const float inv = 1.0f / (float)cnt;
  for (int e = threadIdx.x; e < E_; e += 256) {
    float s = 0.f;
#pragma unroll
    for (int ta = 0; ta < TA_; ++ta) s += embed[(size_t)ai[ta] * E_ + e];
    ap[b * E_ + e] = s * inv;
  }
}

// ---- y[d] = sum_j v[j] * W[j][d] (+ bias) ---------------------------------
__global__ __launch_bounds__(256) void k_matvecT(const float* __restrict__ v, const float* __restrict__ W,
                                                 const float* __restrict__ bias, float* __restrict__ y,
                                                 int J, int N) {
  __shared__ float v_s[1024];
  for (int i = threadIdx.x; i < J; i += 256) v_s[i] = v[i];
  __syncthreads();
  const int d = blockIdx.x * 256 + threadIdx.x;
  float acc = bias ? bias[d] : 0.f;
  for (int j = 0; j < J; j += 4) {
    acc += v_s[j + 0] * W[(size_t)(j + 0) * N + d];
    acc += v_s[j + 1] * W[(size_t)(j + 1) * N + d];
    acc += v_s[j + 2] * W[(size_t)(j + 2) * N + d];
    acc += v_s[j + 3] * W[(size_t)(j + 3) * N + d];
  }
  y[d] = acc;
}

// ---- u[k] = sum_d wk_w[k][d] * qw[d], k < 512 ------------------------------
__global__ __launch_bounds__(256) void k_u(const float* __restrict__ wk, const float* __restrict__ qw,
                                           float* __restrict__ u) {
  __shared__ float q_s[D_];
  for (int i = threadIdx.x; i < D_; i += 256) q_s[i] = qw[i];
  __syncthreads();
  const int lane = threadIdx.x & 63, wave = threadIdx.x >> 6;
  const int k = blockIdx.x * 4 + wave;
  float p = 0.f;
#pragma unroll
  for (int m = 0; m < 16; ++m) { int d = lane + m * 64; p += wk[(size_t)k * D_ + d] * q_s[d]; }
#pragma unroll
  for (int off = 32; off > 0; off >>= 1) p += __shfl_down(p, off);
  if (lane == 0) u[k] = p;
}

// ---- ag[b][g] = asp_pool[b] @ w_ih[:E] + b_gru ------------------------------
__global__ __launch_bounds__(256) void k_ag(const float* __restrict__ ap, const float* __restrict__ w_ih,
                                            const float* __restrict__ bg, float* __restrict__ ag) {
  __shared__ float a_s[4][E_];
  const int g0 = blockIdx.x * 256, b0 = blockIdx.y * 4;
#pragma unroll
  for (int r = 0; r < 2; ++r) {
    int li = threadIdx.x + r * 256;
    int row = li >> 7, c4 = (li & 127) * 4;
    *(float4*)&a_s[row][c4] = *(const float4*)&ap[(size_t)(b0 + row) * E_ + c4];
  }
  __syncthreads();
  const int g = g0 + threadIdx.x;
  float acc0 = 0.f, acc1 = 0.f, acc2 = 0.f, acc3 = 0.f;
  for (int i4 = 0; i4 < 128; ++i4) {
    const float* wp = &w_ih[(size_t)(i4 * 4) * G3_ + g];
    float w0 = wp[0], w1 = wp[G3_], w2 = wp[2 * G3_], w3 = wp[3 * G3_];
    float4 a0 = *(const float4*)&a_s[0][i4 * 4];
    float4 a1 = *(const float4*)&a_s[1][i4 * 4];
    float4 a2 = *(const float4*)&a_s[2][i4 * 4];
    float4 a3 = *(const float4*)&a_s[3][i4 * 4];
    acc0 += a0.x * w0 + a0.y * w1 + a0.z * w2 + a0.w * w3;
    acc1 += a1.x * w0 + a1.y * w1 + a1.z * w2 + a1.w * w3;
    acc2 += a2.x * w0 + a2.y * w1 + a2.z * w2 + a2.w * w3;
    acc3 += a3.x * w0 + a3.y * w1 + a3.z * w2 + a3.w * w3;
  }
  const float bgv = bg[g];
  ag[(size_t)(b0 + 0) * G3_ + g] = acc0 + bgv;
  ag[(size_t)(b0 + 1) * G3_ + g] = acc1 + bgv;
  ag[(size_t)(b0 + 2) * G3_ + g] = acc2 + bgv;
  ag[(size_t)(b0 + 3) * G3_ + g] = acc3 + bgv;
}

// ---- xg superchunk GEMM via split-bf16 MFMA; B pre-split -------------------
__global__ __launch_bounds__(256) void k_gemm_xg_mfma(const int* __restrict__ tidx,
                                                      const float* __restrict__ embed,
                                                      const unsigned short* __restrict__ Bhg,
                                                      const unsigned short* __restrict__ Blg,
                                                      const float* __restrict__ ag,
                                                      float* __restrict__ xg,
                                                      int sc, int tsc, int tshift) {
  __shared__ __align__(16) unsigned short Ah[64][40], Al[64][40];  // [m][k]
  __shared__ __align__(16) unsigned short Bh[64][40], Bl[64][40];  // [col][k]
  const int tid = threadIdx.x;
  const int g0 = blockIdx.x * 64, m0 = blockIdx.y * 64;
  const int lane = tid & 63, wv = tid >> 6;
  const int wr = wv >> 1, wc = wv & 1;
  const int lr = lane & 15, lk8 = (lane >> 4) * 8;

  const int arow = tid >> 2, ak8 = (tid & 3) * 8;
  const int am = m0 + arow;
  const int ab = am >> tshift;
  const int at = sc * tsc + (am & (tsc - 1));
  const int tix = tidx[ab * T_ + at];
  const float* aptr = embed + (size_t)tix * E_ + ak8;
  const float amask = (tix != 0) ? 1.f : 0.f;

  const int bcol = tid >> 2, bk8 = (tid & 3) * 8;
  const unsigned short* bph = Bhg + (size_t)(g0 + bcol) * E_ + bk8;
  const unsigned short* bpl = Blg + (size_t)(g0 + bcol) * E_ + bk8;

  f32x4_ acc[2][2] = {{{0.f,0.f,0.f,0.f},{0.f,0.f,0.f,0.f}},
                      {{0.f,0.f,0.f,0.f},{0.f,0.f,0.f,0.f}}};

  for (int k0 = 0; k0 < E_; k0 += 32) {
    {
      float fv[8];
      *(float4*)&fv[0] = *(const float4*)(aptr + k0);
      *(float4*)&fv[4] = *(const float4*)(aptr + k0 + 4);
      bf16x8_ h8, l8;
#pragma unroll
      for (int j = 0; j < 8; ++j) {
        const float f = fv[j] * amask;
        const unsigned short hb = f2bf_(f);
        h8[j] = (short)hb;
        l8[j] = (short)f2bf_(f - bf2f_(hb));
      }
      *(bf16x8_*)&Ah[arow][ak8] = h8;
      *(bf16x8_*)&Al[arow][ak8] = l8;
    }
    *(bf16x8_*)&Bh[bcol][bk8] = *(const bf16x8_*)(bph + k0);
    *(bf16x8_*)&Bl[bcol][bk8] = *(const bf16x8_*)(bpl + k0);
    __syncthreads();

    bf16x8_ a_hi[2], a_lo[2], b_hi[2], b_lo[2];
#pragma unroll
    for (int s = 0; s < 2; ++s) {
      a_hi[s] = *(const bf16x8_*)&Ah[wr * 32 + s * 16 + lr][lk8];
      a_lo[s] = *(const bf16x8_*)&Al[wr * 32 + s * 16 + lr][lk8];
      b_hi[s] = *(const bf16x8_*)&Bh[wc * 32 + s * 16 + lr][lk8];
      b_lo[s] = *(const bf16x8_*)&Bl[wc * 32 + s * 16 + lr][lk8];
    }
#pragma unroll
    for (int sr = 0; sr < 2; ++sr)
#pragma unroll
      for (int sc2 = 0; sc2 < 2; ++sc2) {
        acc[sr][sc2] = __builtin_amdgcn_mfma_f32_16x16x32_bf16(a_hi[sr], b_hi[sc2], acc[sr][sc2], 0, 0, 0);
        acc[sr][sc2] = __builtin_amdgcn_mfma_f32_16x16x32_bf16(a_hi[sr], b_lo[sc2], acc[sr][sc2], 0, 0, 0);
        acc[sr][sc2] = __builtin_amdgcn_mfma_f32_16x16x32_bf16(a_lo[sr], b_hi[sc2], acc[sr][sc2], 0, 0, 0);
      }
    __syncthreads();
  }

#pragma unroll
  for (int sr = 0; sr < 2; ++sr)
#pragma unroll
    for (int sc2 = 0; sc2 < 2; ++sc2)
#pragma unroll
      for (int r = 0; r < 4; ++r) {
        const int m = m0 + wr * 32 + sr * 16 + (lane >> 4) * 4 + r;
        const int g = g0 + wc * 32 + sc2 * 16 + lr;
        const int b = m >> tshift;
        xg[(size_t)m * G3_ + g] = acc[sr][sc2][r] + ag[(size_t)b * G3_ + g];
      }
}

// ---- persistent GRU superchunk: tagged data-flow sync, 2 barriers/step -----
// Round-15 structure; staging now ISSUES all 16 tagged loads upfront but
// polls/converts in two 8-entry passes: half 0's convert work overlaps
// half 1's in-flight loads (partial vmcnt), retry pass stays 8-wide.
__global__ __launch_bounds__(512, 2) void k_gru_chunk(const float* __restrict__ whhT,
                                                      const float* __restrict__ xg,
                                                      unsigned long long* __restrict__ hA,
                                                      unsigned long long* __restrict__ hB,
                                                      float* __restrict__ hs,
                                                      int sc, int tsc) {
  __shared__ __align__(16) unsigned short h_hi_s[16 * 520];
  __shared__ __align__(16) unsigned short h_lo_s[16 * 520];
  __shared__ float hexact_s[16][16];
  __shared__ __align__(16) float cbuf_s[3][2][64][4];

  const int tid = threadIdx.x;
  const int kg = blockIdx.x >> 3;
  const int bg = blockIdx.x & 7;
  const int k0 = kg * 16, b0 = bg * 16;
  const int lane = tid & 63, wv = tid >> 6;
  const int gate = wv >> 1, kseg = wv & 1;      // valid for wv<6
  const int lrow = lane & 15, lhi = lane >> 4;
  const int gb = tid >> 4, tx = tid & 15;       // gate-math map (tid<256)

  // ---- pre-split weight B-fragments into registers (once per launch) -------
  bf16x8_ bhi[8], blo[8];
  if (wv < 6) {
    const float* wp = &whhT[((size_t)(gate * H_ + k0 + lrow)) * H_ + kseg * 256 + lhi * 8];
#pragma unroll
    for (int ks = 0; ks < 8; ++ks) {
      float fv[8];
      *(float4*)&fv[0] = *(const float4*)(wp + ks * 32);
      *(float4*)&fv[4] = *(const float4*)(wp + ks * 32 + 4);
      bf16x8_ h8, l8;
#pragma unroll
      for (int j = 0; j < 8; ++j) {
        const unsigned short hb = f2bf_(fv[j]);
        h8[j] = (short)hb;
        l8[j] = (short)f2bf_(fv[j] - bf2f_(hb));
      }
      bhi[ks] = h8; blo[ks] = l8;
    }
  }

  for (int tcc = 0; tcc < tsc; ++tcc) {
    const int t = sc * tsc + tcc;
    const unsigned long long* hsrc = (t & 1) ? hB : hA;
    unsigned long long*       hdst = (t & 1) ? hA : hB;
    const unsigned tagc = (unsigned)t;

    // hoisted xg loads (independent of h -> overlap poll latency)
    float xr = 0.f, xz = 0.f, xn = 0.f;
    if (tid < 256) {
      const float* xrow = xg + ((size_t)(b0 + gb) * tsc + tcc) * G3_;
      const int k = k0 + tx;
      xr = xrow[k]; xz = xrow[H_ + k]; xn = xrow[2 * H_ + k];
    }

    // ---- tagged staging: thread owns column tid across 16 rows (coalesced).
    //      Issue ALL 16 loads upfront; poll/convert in two 8-entry passes. ---
    {
      unsigned long long v[16];
#pragma unroll
      for (int ii = 0; ii < 16; ++ii)
        v[ii] = __hip_atomic_load(&hsrc[(size_t)(b0 + ii) * H_ + tid],
                                  __ATOMIC_RELAXED, __HIP_MEMORY_SCOPE_AGENT);
#pragma unroll
      for (int half = 0; half < 2; ++half) {
        unsigned pend = 0xFFu;
        while (pend) {
#pragma unroll
          for (int ii = 0; ii < 8; ++ii) {
            if ((pend >> ii) & 1u) {
              const int r = half * 8 + ii;
              if ((unsigned)(v[r] >> 32) == tagc) {
                const float f = __uint_as_float((unsigned)(v[r] & 0xFFFFFFFFull));
                const unsigned short hb = f2bf_(f);
                h_hi_s[r * 520 + tid] = hb;
                h_lo_s[r * 520 + tid] = f2bf_(f - bf2f_(hb));
                if ((unsigned)(tid - k0) < 16u) hexact_s[r][tid - k0] = f;
                pend &= ~(1u << ii);
              } else {
                v[r] = __hip_atomic_load(&hsrc[(size_t)(b0 + r) * H_ + tid],
                                         __ATOMIC_RELAXED, __HIP_MEMORY_SCOPE_AGENT);
              }
            }
          }
          if (pend) __builtin_amdgcn_s_sleep(1);
        }
      }
    }
    __syncthreads();                       // B1

    // ---- MFMA phase: 8 Ksteps x 3 split-terms per active wave ---------------
    if (wv < 6) {
      f32x4_ c = {0.f, 0.f, 0.f, 0.f};
      const int abase = lrow * 520 + kseg * 256 + lhi * 8;
#pragma unroll
      for (int ks = 0; ks < 8; ++ks) {
        const bf16x8_ ahi = *(const bf16x8_*)&h_hi_s[abase + ks * 32];
        const bf16x8_ alo = *(const bf16x8_*)&h_lo_s[abase + ks * 32];
        c = __builtin_amdgcn_mfma_f32_16x16x32_bf16(ahi, bhi[ks], c, 0, 0, 0);
        c = __builtin_amdgcn_mfma_f32_16x16x32_bf16(ahi, blo[ks], c, 0, 0, 0);
        c = __builtin_amdgcn_mfma_f32_16x16x32_bf16(alo, bhi[ks], c, 0, 0, 0);
      }
      *(f32x4_*)&cbuf_s[gate][kseg][lane][0] = c;
    }
    __syncthreads();                       // B2

    // ---- gate math: read both kseg fragments directly (tid<256) -------------
    if (tid < 256) {
      const int lane2 = ((gb >> 2) << 4) | tx;   // frag: row=(lane>>4)*4+reg
      const int reg = gb & 3;
      const float sR = cbuf_s[0][0][lane2][reg] + cbuf_s[0][1][lane2][reg];
      const float sZ = cbuf_s[1][0][lane2][reg] + cbuf_s[1][1][lane2][reg];
      const float sN = cbuf_s[2][0][lane2][reg] + cbuf_s[2][1][lane2][reg];
      const float hp = hexact_s[gb][tx];
      const float gr = sigmoidf_(xr + sR);
      const float gz = sigmoidf_(xz + sZ);
      const float gn = tanhf(xn + gr * sN);
      const float hv = (1.f - gz) * gn + gz * hp;
      const int k = k0 + tx;
      __hip_atomic_store(&hdst[(size_t)(b0 + gb) * H_ + k],
                         ((unsigned long long)(unsigned)(t + 1) << 32) |
                             (unsigned long long)__float_as_uint(hv),
                         __ATOMIC_RELAXED, __HIP_MEMORY_SCOPE_AGENT);
      hs[((size_t)(b0 + gb) * T_ + t) * H_ + k] = hv;
    }
  }
}

// ---- logits[b][t] = hs[b][t] . u -------------------------------------------
__global__ __launch_bounds__(256) void k_logits(const float* __restrict__ hs, const float* __restrict__ u,
                                                float* __restrict__ lg) {
  __shared__ float u_s[H_];
  for (int i = threadIdx.x; i < H_; i += 256) u_s[i] = u[i];
  __syncthreads();
  const int lane = threadIdx.x & 63, wave = threadIdx.x >> 6;
  const int wid = blockIdx.x * 4 + wave;
  const float* hrow = hs + (size_t)wid * H_;
  float p = 0.f;
#pragma unroll
  for (int m = 0; m < 8; ++m) { int d = lane + m * 64; p += hrow[d] * u_s[d]; }
#pragma unroll
  for (int off = 32; off > 0; off >>= 1) p += __shfl_down(p, off);
  if (lane == 0) lg[wid] = p;
}

// ---- softmax over t + weighted pooling -------------------------------------
__global__ __launch_bounds__(256) void k_softmax_pool(const float* __restrict__ lg, const float* __restrict__ hs,
                                                      float* __restrict__ pooled) {
  __shared__ float sw[256];
  __shared__ float red[8];
  const int b = blockIdx.x, tid = threadIdx.x;
  const int lane = tid & 63, wave = tid >> 6;
  const float lv = lg[b * T_ + tid];
  float mx = lv;
#pragma unroll
  for (int off = 32; off > 0; off >>= 1) mx = fmaxf(mx, __shfl_down(mx, off));
  if (lane == 0) red[wave] = mx;
  __syncthreads();
  if (tid == 0) red[4] = fmaxf(fmaxf(red[0], red[1]), fmaxf(red[2], red[3]));
  __syncthreads();
  mx = red[4];
  const float p = __expf(lv - mx);
  float sm = p;
#pragma unroll
  for (int off = 32; off > 0; off >>= 1) sm += __shfl_down(sm, off);
  if (lane == 0) red[wave] = sm;
  __syncthreads();
  if (tid == 0) red[5] = red[0] + red[1] + red[2] + red[3];
  __syncthreads();
  sw[tid] = p / red[5];
  __syncthreads();
  float a0 = 0.f, a1 = 0.f;
  const float* hbase = hs + (size_t)b * T_ * H_;
  for (int t = 0; t < T_; ++t) {
    const float s = sw[t];
    a0 += s * hbase[(size_t)t * H_ + tid];
    a1 += s * hbase[(size_t)t * H_ + 256 + tid];
  }
  pooled[b * H_ + tid] = a0;
  pooled[b * H_ + 256 + tid] = a1;
}

// ---- final dense (H->3) ----------------------------------------------------
__global__ __launch_bounds__(64) void k_dense(const float* __restrict__ pooled, const float* __restrict__ dw,
                                              const float* __restrict__ db, float* __restrict__ out) {
  const int b = blockIdx.x, lane = threadIdx.x;
  float a0 = 0.f, a1 = 0.f, a2 = 0.f;
#pragma unroll
  for (int m = 0; m < 8; ++m) {
    int h = lane + m * 64;
    float pv = pooled[b * H_ + h];
    a0 += pv * dw[h * 3 + 0];
    a1 += pv * dw[h * 3 + 1];
    a2 += pv * dw[h * 3 + 2];
  }
#pragma unroll
  for (int off = 32; off > 0; off >>= 1) {
    a0 += __shfl_down(a0, off);
    a1 += __shfl_down(a1, off);
    a2 += __shfl_down(a2, off);
  }
  if (lane == 0) {
    out[b * 3 + 0] = a0 + db[0];
    out[b * 3 + 1] = a1 + db[1];
    out[b * 3 + 2] = a2 + db[2];
  }
}

extern "C" void kernel_launch(void* const* d_in, const int* in_sizes, int n_in,
                              void* d_out, int out_size, void* d_ws, size_t ws_size,
                              hipStream_t stream) {
  (void)in_sizes; (void)n_in; (void)out_size;
  const int*   tidx  = (const int*)d_in[0];
  const int*   aidx  = (const int*)d_in[1];
  const float* embed = (const float*)d_in[2];
  const float* w_ih  = (const float*)d_in[3];
  const float* w_hh  = (const float*)d_in[4];
  const float* b_gru = (const float*)d_in[5];
  const float* wk_w  = (const float*)d_in[6];
  // d_in[7] = wk_b: cancels in softmax, unused
  const float* wq_w  = (const float*)d_in[8];
  const float* wq_b  = (const float*)d_in[9];
  const float* q_p   = (const float*)d_in[10];
  const float* bil_w = (const float*)d_in[11];
  const float* dw    = (const float*)d_in[12];
  const float* db    = (const float*)d_in[13];
  float* out = (float*)d_out;

  // choose superchunk length by workspace capacity (deterministic: ws_size fixed)
  const size_t fixed_floats =
      (size_t)B_ * H_ * 2 * 2 +          // hA64 + hB64 (u64 as 2 floats)
      (size_t)G3_ * E_ / 2 * 2 +         // Bhg + Blg (u16 as half floats)
      (size_t)B_ * E_ + (size_t)B_ * G3_ + D_ + D_ + H_ +
      (size_t)B_ * T_ + (size_t)B_ * H_ +
      (size_t)G3_ * H_ + (size_t)B_ * T_ * H_;
  int TSC = 64, TSHIFT = 6;
  if ((fixed_floats + (size_t)B_ * 64 * G3_) * 4 > ws_size) { TSC = 16; TSHIFT = 4; }
  const int NSC = T_ / TSC;

  float* ws = (float*)d_ws;
  size_t off = 0;
  unsigned long long* hA64 = (unsigned long long*)(ws + off); off += (size_t)B_ * H_ * 2;
  unsigned long long* hB64 = (unsigned long long*)(ws + off); off += (size_t)B_ * H_ * 2;
  unsigned short* Bhg = (unsigned short*)(ws + off); off += (size_t)G3_ * E_ / 2;
  unsigned short* Blg = (unsigned short*)(ws + off); off += (size_t)G3_ * E_ / 2;
  float* ap     = ws + off; off += (size_t)B_ * E_;
  float* ag     = ws + off; off += (size_t)B_ * G3_;
  float* qx     = ws + off; off += D_;
  float* qw     = ws + off; off += D_;
  float* u      = ws + off; off += H_;
  float* lg     = ws + off; off += (size_t)B_ * T_;
  float* pooled = ws + off; off += (size_t)B_ * H_;
  float* whhT   = ws + off; off += (size_t)G3_ * H_;
  float* xgbuf  = ws + off; off += (size_t)B_ * TSC * G3_;
  float* hs     = ws + off; off += (size_t)B_ * T_ * H_;

  // zero both tagged h buffers: hA supplies {h=0, tag=0} for step 0; clean
  // tags every launch make graph replays independent of leftover state.
  hipMemsetAsync(hA64, 0, (size_t)B_ * H_ * 2 * sizeof(unsigned long long), stream);

  k_transpose<<<dim3(48, 16), 256, 0, stream>>>(w_hh, whhT);
  k_prep_bsplit<<<dim3(48, 16), 256, 0, stream>>>(w_ih, Bhg, Blg);
  k_asp_pool<<<B_, 256, 0, stream>>>(aidx, embed, ap);
  k_matvecT<<<4, 256, 0, stream>>>(q_p, wq_w, wq_b, qx, D_, D_);
  k_matvecT<<<4, 256, 0, stream>>>(qx, bil_w, nullptr, qw, D_, D_);
  k_u<<<128, 256, 0, stream>>>(wk_w, qw, u);
  k_ag<<<dim3(6, 32), 256, 0, stream>>>(ap, w_ih, b_gru, ag);

  for (int sc = 0; sc < NSC; ++sc) {
    k_gemm_xg_mfma<<<dim3(24, B_ * TSC / 64), 256, 0, stream>>>(
        tidx, embed, Bhg, Blg, ag, xgbuf, sc, TSC, TSHIFT);
    int scA = sc, tscA = TSC;
    void* args[] = { (void*)&whhT, (void*)&xgbuf, (void*)&hA64, (void*)&hB64,
                     (void*)&hs, (void*)&scA, (void*)&tscA };
    hipLaunchCooperativeKernel((const void*)k_gru_chunk, dim3(256), dim3(512),
                               args, 0, stream);
  }

  k_logits<<<8192, 256, 0, stream>>>(hs, u, lg);
  k_softmax_pool<<<B_, 256, 0, stream>>>(lg, hs, pooled);
  k_dense<<<B_, 64, 0, stream>>>(pooled, dw, db, out);
}

// Round 17
// 2013.849 us; speedup vs baseline: 1.1658x; 1.1658x over previous
//
#include <hip/hip_runtime.h>
#include <hip/hip_bf16.h>

#define B_ 128
#define T_ 256
#define TA_ 8
#define E_ 512
#define H_ 512
#define D_ 1024
#define G3_ 1536

typedef __attribute__((ext_vector_type(8))) short bf16x8_;
typedef __attribute__((ext_vector_type(4))) float f32x4_;

__device__ __forceinline__ float sigmoidf_(float x) { return 1.0f / (1.0f + __expf(-x)); }

__device__ __forceinline__ unsigned short f2bf_(float f) {
  unsigned u = __float_as_uint(f);
  return (unsigned short)((u + 0x7FFFu + ((u >> 16) & 1u)) >> 16);   // RNE
}
__device__ __forceinline__ float bf2f_(unsigned short b) {
  return __uint_as_float((unsigned)b << 16);
}

// ---- transpose w_hh (512 x 1536) -> w_hhT (1536 x 512) -------------------
__global__ __launch_bounds__(256) void k_transpose(const float* __restrict__ w, float* __restrict__ wt) {
  __shared__ float tile[32][33];
  const int tx = threadIdx.x & 31, ty = threadIdx.x >> 5;
  const int c0 = blockIdx.x * 32, i0 = blockIdx.y * 32;
#pragma unroll
  for (int r = 0; r < 4; ++r) {
    int ii = ty + r * 8;
    tile[ii][tx] = w[(size_t)(i0 + ii) * G3_ + c0 + tx];
  }
  __syncthreads();
#pragma unroll
  for (int r = 0; r < 4; ++r) {
    int cc = ty + r * 8;
    wt[(size_t)(c0 + cc) * H_ + i0 + tx] = tile[tx][cc];
  }
}

// ---- pre-split w_ih[E:2E] -> bf16 hi/lo, transposed to [col][k] ------------
__global__ __launch_bounds__(256) void k_prep_bsplit(const float* __restrict__ w_ih,
                                                     unsigned short* __restrict__ Bhg,
                                                     unsigned short* __restrict__ Blg) {
  __shared__ float tile[32][33];
  const int tx = threadIdx.x & 31, ty = threadIdx.x >> 5;
  const int g0 = blockIdx.x * 32, kk0 = blockIdx.y * 32;
#pragma unroll
  for (int r = 0; r < 4; ++r) {
    int kl = ty + r * 8;
    tile[kl][tx] = w_ih[(size_t)(E_ + kk0 + kl) * G3_ + g0 + tx];
  }
  __syncthreads();
#pragma unroll
  for (int r = 0; r < 4; ++r) {
    const int gl = ty + r * 8;
    const float f = tile[tx][gl];            // w[kk0+tx][g0+gl]
    const unsigned short hb = f2bf_(f);
    Bhg[(size_t)(g0 + gl) * E_ + kk0 + tx] = hb;
    Blg[(size_t)(g0 + gl) * E_ + kk0 + tx] = f2bf_(f - bf2f_(hb));
  }
}

// ---- aspect mean pooling --------------------------------------------------
__global__ __launch_bounds__(256) void k_asp_pool(const int* __restrict__ aidx, const float* __restrict__ embed,
                                                  float* __restrict__ ap) {
  const int b = blockIdx.x;
  int ai[TA_]; int cnt = 0;
#pragma unroll
  for (int ta = 0; ta < TA_; ++ta) { ai[ta] = aidx[b * TA_ + ta]; cnt += (ai[ta] != 0); }
  const float inv = 1.0f / (float)cnt;
  for (int e = threadIdx.x; e < E_; e += 256) {
    float s = 0.f;
#pragma unroll
    for (int ta = 0; ta < TA_; ++ta) s += embed[(size_t)ai[ta] * E_ + e];
    ap[b * E_ + e] = s * inv;
  }
}

// ---- y[d] = sum_j v[j] * W[j][d] (+ bias) ---------------------------------
__global__ __launch_bounds__(256) void k_matvecT(const float* __restrict__ v, const float* __restrict__ W,
                                                 const float* __restrict__ bias, float* __restrict__ y,
                                                 int J, int N) {
  __shared__ float v_s[1024];
  for (int i = threadIdx.x; i < J; i += 256) v_s[i] = v[i];
  __syncthreads();
  const int d = blockIdx.x * 256 + threadIdx.x;
  float acc = bias ? bias[d] : 0.f;
  for (int j = 0; j < J; j += 4) {
    acc += v_s[j + 0] * W[(size_t)(j + 0) * N + d];
    acc += v_s[j + 1] * W[(size_t)(j + 1) * N + d];
    acc += v_s[j + 2] * W[(size_t)(j + 2) * N + d];
    acc += v_s[j + 3] * W[(size_t)(j + 3) * N + d];
  }
  y[d] = acc;
}

// ---- u[k] = sum_d wk_w[k][d] * qw[d], k < 512 ------------------------------
__global__ __launch_bounds__(256) void k_u(const float* __restrict__ wk, const float* __restrict__ qw,
                                           float* __restrict__ u) {
  __shared__ float q_s[D_];
  for (int i = threadIdx.x; i < D_; i += 256) q_s[i] = qw[i];
  __syncthreads();
  const int lane = threadIdx.x & 63, wave = threadIdx.x >> 6;
  const int k = blockIdx.x * 4 + wave;
  float p = 0.f;
#pragma unroll
  for (int m = 0; m < 16; ++m) { int d = lane + m * 64; p += wk[(size_t)k * D_ + d] * q_s[d]; }
#pragma unroll
  for (int off = 32; off > 0; off >>= 1) p += __shfl_down(p, off);
  if (lane == 0) u[k] = p;
}

// ---- ag[b][g] = asp_pool[b] @ w_ih[:E] + b_gru ------------------------------
__global__ __launch_bounds__(256) void k_ag(const float* __restrict__ ap, const float* __restrict__ w_ih,
                                            const float* __restrict__ bg, float* __restrict__ ag) {
  __shared__ float a_s[4][E_];
  const int g0 = blockIdx.x * 256, b0 = blockIdx.y * 4;
#pragma unroll
  for (int r = 0; r < 2; ++r) {
    int li = threadIdx.x + r * 256;
    int row = li >> 7, c4 = (li & 127) * 4;
    *(float4*)&a_s[row][c4] = *(const float4*)&ap[(size_t)(b0 + row) * E_ + c4];
  }
  __syncthreads();
  const int g = g0 + threadIdx.x;
  float acc0 = 0.f, acc1 = 0.f, acc2 = 0.f, acc3 = 0.f;
  for (int i4 = 0; i4 < 128; ++i4) {
    const float* wp = &w_ih[(size_t)(i4 * 4) * G3_ + g];
    float w0 = wp[0], w1 = wp[G3_], w2 = wp[2 * G3_], w3 = wp[3 * G3_];
    float4 a0 = *(const float4*)&a_s[0][i4 * 4];
    float4 a1 = *(const float4*)&a_s[1][i4 * 4];
    float4 a2 = *(const float4*)&a_s[2][i4 * 4];
    float4 a3 = *(const float4*)&a_s[3][i4 * 4];
    acc0 += a0.x * w0 + a0.y * w1 + a0.z * w2 + a0.w * w3;
    acc1 += a1.x * w0 + a1.y * w1 + a1.z * w2 + a1.w * w3;
    acc2 += a2.x * w0 + a2.y * w1 + a2.z * w2 + a2.w * w3;
    acc3 += a3.x * w0 + a3.y * w1 + a3.z * w2 + a3.w * w3;
  }
  const float bgv = bg[g];
  ag[(size_t)(b0 + 0) * G3_ + g] = acc0 + bgv;
  ag[(size_t)(b0 + 1) * G3_ + g] = acc1 + bgv;
  ag[(size_t)(b0 + 2) * G3_ + g] = acc2 + bgv;
  ag[(size_t)(b0 + 3) * G3_ + g] = acc3 + bgv;
}

// ---- xg superchunk GEMM via split-bf16 MFMA; B pre-split -------------------
__global__ __launch_bounds__(256) void k_gemm_xg_mfma(const int* __restrict__ tidx,
                                                      const float* __restrict__ embed,
                                                      const unsigned short* __restrict__ Bhg,
                                                      const unsigned short* __restrict__ Blg,
                                                      const float* __restrict__ ag,
                                                      float* __restrict__ xg,
                                                      int sc, int tsc, int tshift) {
  __shared__ __align__(16) unsigned short Ah[64][40], Al[64][40];  // [m][k]
  __shared__ __align__(16) unsigned short Bh[64][40], Bl[64][40];  // [col][k]
  const int tid = threadIdx.x;
  const int g0 = blockIdx.x * 64, m0 = blockIdx.y * 64;
  const int lane = tid & 63, wv = tid >> 6;
  const int wr = wv >> 1, wc = wv & 1;
  const int lr = lane & 15, lk8 = (lane >> 4) * 8;

  const int arow = tid >> 2, ak8 = (tid & 3) * 8;
  const int am = m0 + arow;
  const int ab = am >> tshift;
  const int at = sc * tsc + (am & (tsc - 1));
  const int tix = tidx[ab * T_ + at];
  const float* aptr = embed + (size_t)tix * E_ + ak8;
  const float amask = (tix != 0) ? 1.f : 0.f;

  const int bcol = tid >> 2, bk8 = (tid & 3) * 8;
  const unsigned short* bph = Bhg + (size_t)(g0 + bcol) * E_ + bk8;
  const unsigned short* bpl = Blg + (size_t)(g0 + bcol) * E_ + bk8;

  f32x4_ acc[2][2] = {{{0.f,0.f,0.f,0.f},{0.f,0.f,0.f,0.f}},
                      {{0.f,0.f,0.f,0.f},{0.f,0.f,0.f,0.f}}};

  for (int k0 = 0; k0 < E_; k0 += 32) {
    {
      float fv[8];
      *(float4*)&fv[0] = *(const float4*)(aptr + k0);
      *(float4*)&fv[4] = *(const float4*)(aptr + k0 + 4);
      bf16x8_ h8, l8;
#pragma unroll
      for (int j = 0; j < 8; ++j) {
        const float f = fv[j] * amask;
        const unsigned short hb = f2bf_(f);
        h8[j] = (short)hb;
        l8[j] = (short)f2bf_(f - bf2f_(hb));
      }
      *(bf16x8_*)&Ah[arow][ak8] = h8;
      *(bf16x8_*)&Al[arow][ak8] = l8;
    }
    *(bf16x8_*)&Bh[bcol][bk8] = *(const bf16x8_*)(bph + k0);
    *(bf16x8_*)&Bl[bcol][bk8] = *(const bf16x8_*)(bpl + k0);
    __syncthreads();

    bf16x8_ a_hi[2], a_lo[2], b_hi[2], b_lo[2];
#pragma unroll
    for (int s = 0; s < 2; ++s) {
      a_hi[s] = *(const bf16x8_*)&Ah[wr * 32 + s * 16 + lr][lk8];
      a_lo[s] = *(const bf16x8_*)&Al[wr * 32 + s * 16 + lr][lk8];
      b_hi[s] = *(const bf16x8_*)&Bh[wc * 32 + s * 16 + lr][lk8];
      b_lo[s] = *(const bf16x8_*)&Bl[wc * 32 + s * 16 + lr][lk8];
    }
#pragma unroll
    for (int sr = 0; sr < 2; ++sr)
#pragma unroll
      for (int sc2 = 0; sc2 < 2; ++sc2) {
        acc[sr][sc2] = __builtin_amdgcn_mfma_f32_16x16x32_bf16(a_hi[sr], b_hi[sc2], acc[sr][sc2], 0, 0, 0);
        acc[sr][sc2] = __builtin_amdgcn_mfma_f32_16x16x32_bf16(a_hi[sr], b_lo[sc2], acc[sr][sc2], 0, 0, 0);
        acc[sr][sc2] = __builtin_amdgcn_mfma_f32_16x16x32_bf16(a_lo[sr], b_hi[sc2], acc[sr][sc2], 0, 0, 0);
      }
    __syncthreads();
  }

#pragma unroll
  for (int sr = 0; sr < 2; ++sr)
#pragma unroll
    for (int sc2 = 0; sc2 < 2; ++sc2)
#pragma unroll
      for (int r = 0; r < 4; ++r) {
        const int m = m0 + wr * 32 + sr * 16 + (lane >> 4) * 4 + r;
        const int g = g0 + wc * 32 + sc2 * 16 + lr;
        const int b = m >> tshift;
        xg[(size_t)m * G3_ + g] = acc[sr][sc2][r] + ag[(size_t)b * G3_ + g];
      }
}

// ---- persistent GRU superchunk: tagged data-flow sync, 2 barriers/step -----
// Round-15 version (measured best: 402 µs/chunk, 6.28 µs/step). 2-half
// coalesced poll with inline convert; cbuf-direct gate read.
// Per step: [poll/stage] B1 [mfma->cbuf] B2 [gate].
__global__ __launch_bounds__(512, 2) void k_gru_chunk(const float* __restrict__ whhT,
                                                      const float* __restrict__ xg,
                                                      unsigned long long* __restrict__ hA,
                                                      unsigned long long* __restrict__ hB,
                                                      float* __restrict__ hs,
                                                      int sc, int tsc) {
  __shared__ __align__(16) unsigned short h_hi_s[16 * 520];
  __shared__ __align__(16) unsigned short h_lo_s[16 * 520];
  __shared__ float hexact_s[16][16];
  __shared__ __align__(16) float cbuf_s[3][2][64][4];

  const int tid = threadIdx.x;
  const int kg = blockIdx.x >> 3;
  const int bg = blockIdx.x & 7;
  const int k0 = kg * 16, b0 = bg * 16;
  const int lane = tid & 63, wv = tid >> 6;
  const int gate = wv >> 1, kseg = wv & 1;      // valid for wv<6
  const int lrow = lane & 15, lhi = lane >> 4;
  const int gb = tid >> 4, tx = tid & 15;       // gate-math map (tid<256)

  // ---- pre-split weight B-fragments into registers (once per launch) -------
  bf16x8_ bhi[8], blo[8];
  if (wv < 6) {
    const float* wp = &whhT[((size_t)(gate * H_ + k0 + lrow)) * H_ + kseg * 256 + lhi * 8];
#pragma unroll
    for (int ks = 0; ks < 8; ++ks) {
      float fv[8];
      *(float4*)&fv[0] = *(const float4*)(wp + ks * 32);
      *(float4*)&fv[4] = *(const float4*)(wp + ks * 32 + 4);
      bf16x8_ h8, l8;
#pragma unroll
      for (int j = 0; j < 8; ++j) {
        const unsigned short hb = f2bf_(fv[j]);
        h8[j] = (short)hb;
        l8[j] = (short)f2bf_(fv[j] - bf2f_(hb));
      }
      bhi[ks] = h8; blo[ks] = l8;
    }
  }

  for (int tcc = 0; tcc < tsc; ++tcc) {
    const int t = sc * tsc + tcc;
    const unsigned long long* hsrc = (t & 1) ? hB : hA;
    unsigned long long*       hdst = (t & 1) ? hA : hB;
    const unsigned tagc = (unsigned)t;

    // hoisted xg loads (independent of h -> overlap poll latency)
    float xr = 0.f, xz = 0.f, xn = 0.f;
    if (tid < 256) {
      const float* xrow = xg + ((size_t)(b0 + gb) * tsc + tcc) * G3_;
      const int k = k0 + tx;
      xr = xrow[k]; xz = xrow[H_ + k]; xn = xrow[2 * H_ + k];
    }

    // ---- tagged staging: thread owns column tid across 16 rows (coalesced) --
#pragma unroll
    for (int half = 0; half < 2; ++half) {
      unsigned long long v[8];
#pragma unroll
      for (int ii = 0; ii < 8; ++ii)
        v[ii] = __hip_atomic_load(&hsrc[(size_t)(b0 + half * 8 + ii) * H_ + tid],
                                  __ATOMIC_RELAXED, __HIP_MEMORY_SCOPE_AGENT);
      unsigned pend = 0xFFu;
      while (pend) {
#pragma unroll
        for (int ii = 0; ii < 8; ++ii) {
          if ((pend >> ii) & 1u) {
            if ((unsigned)(v[ii] >> 32) == tagc) {
              union { unsigned u; float f; } cv;
              cv.u = (unsigned)(v[ii] & 0xFFFFFFFFull);
              const int r = half * 8 + ii;
              const unsigned short hb = f2bf_(cv.f);
              h_hi_s[r * 520 + tid] = hb;
              h_lo_s[r * 520 + tid] = f2bf_(cv.f - bf2f_(hb));
              if ((unsigned)(tid - k0) < 16u) hexact_s[r][tid - k0] = cv.f;
              pend &= ~(1u << ii);
            } else {
              v[ii] = __hip_atomic_load(&hsrc[(size_t)(b0 + half * 8 + ii) * H_ + tid],
                                        __ATOMIC_RELAXED, __HIP_MEMORY_SCOPE_AGENT);
            }
          }
        }
        if (pend) __builtin_amdgcn_s_sleep(1);
      }
    }
    __syncthreads();                       // B1

    // ---- MFMA phase: 8 Ksteps x 3 split-terms per active wave ---------------
    if (wv < 6) {
      f32x4_ c = {0.f, 0.f, 0.f, 0.f};
      const int abase = lrow * 520 + kseg * 256 + lhi * 8;
#pragma unroll
      for (int ks = 0; ks < 8; ++ks) {
        const bf16x8_ ahi = *(const bf16x8_*)&h_hi_s[abase + ks * 32];
        const bf16x8_ alo = *(const bf16x8_*)&h_lo_s[abase + ks * 32];
        c = __builtin_amdgcn_mfma_f32_16x16x32_bf16(ahi, bhi[ks], c, 0, 0, 0);
        c = __builtin_amdgcn_mfma_f32_16x16x32_bf16(ahi, blo[ks], c, 0, 0, 0);
        c = __builtin_amdgcn_mfma_f32_16x16x32_bf16(alo, bhi[ks], c, 0, 0, 0);
      }
      *(f32x4_*)&cbuf_s[gate][kseg][lane][0] = c;
    }
    __syncthreads();                       // B2

    // ---- gate math: read both kseg fragments directly (tid<256) -------------
    if (tid < 256) {
      const int lane2 = ((gb >> 2) << 4) | tx;   // frag: row=(lane>>4)*4+reg
      const int reg = gb & 3;
      const float sR = cbuf_s[0][0][lane2][reg] + cbuf_s[0][1][lane2][reg];
      const float sZ = cbuf_s[1][0][lane2][reg] + cbuf_s[1][1][lane2][reg];
      const float sN = cbuf_s[2][0][lane2][reg] + cbuf_s[2][1][lane2][reg];
      const float hp = hexact_s[gb][tx];
      const float gr = sigmoidf_(xr + sR);
      const float gz = sigmoidf_(xz + sZ);
      const float gn = tanhf(xn + gr * sN);
      const float hv = (1.f - gz) * gn + gz * hp;
      const int k = k0 + tx;
      __hip_atomic_store(&hdst[(size_t)(b0 + gb) * H_ + k],
                         ((unsigned long long)(unsigned)(t + 1) << 32) |
                             (unsigned long long)__float_as_uint(hv),
                         __ATOMIC_RELAXED, __HIP_MEMORY_SCOPE_AGENT);
      hs[((size_t)(b0 + gb) * T_ + t) * H_ + k] = hv;
    }
  }
}

// ---- logits[b][t] = hs[b][t] . u -------------------------------------------
__global__ __launch_bounds__(256) void k_logits(const float* __restrict__ hs, const float* __restrict__ u,
                                                float* __restrict__ lg) {
  __shared__ float u_s[H_];
  for (int i = threadIdx.x; i < H_; i += 256) u_s[i] = u[i];
  __syncthreads();
  const int lane = threadIdx.x & 63, wave = threadIdx.x >> 6;
  const int wid = blockIdx.x * 4 + wave;
  const float* hrow = hs + (size_t)wid * H_;
  float p = 0.f;
#pragma unroll
  for (int m = 0; m < 8; ++m) { int d = lane + m * 64; p += hrow[d] * u_s[d]; }
#pragma unroll
  for (int off = 32; off > 0; off >>= 1) p += __shfl_down(p, off);
  if (lane == 0) lg[wid] = p;
}

// ---- softmax over t + weighted pooling -------------------------------------
__global__ __launch_bounds__(256) void k_softmax_pool(const float* __restrict__ lg, const float* __restrict__ hs,
                                                      float* __restrict__ pooled) {
  __shared__ float sw[256];
  __shared__ float red[8];
  const int b = blockIdx.x, tid = threadIdx.x;
  const int lane = tid & 63, wave = tid >> 6;
  const float lv = lg[b * T_ + tid];
  float mx = lv;
#pragma unroll
  for (int off = 32; off > 0; off >>= 1) mx = fmaxf(mx, __shfl_down(mx, off));
  if (lane == 0) red[wave] = mx;
  __syncthreads();
  if (tid == 0) red[4] = fmaxf(fmaxf(red[0], red[1]), fmaxf(red[2], red[3]));
  __syncthreads();
  mx = red[4];
  const float p = __expf(lv - mx);
  float sm = p;
#pragma unroll
  for (int off = 32; off > 0; off >>= 1) sm += __shfl_down(sm, off);
  if (lane == 0) red[wave] = sm;
  __syncthreads();
  if (tid == 0) red[5] = red[0] + red[1] + red[2] + red[3];
  __syncthreads();
  sw[tid] = p / red[5];
  __syncthreads();
  float a0 = 0.f, a1 = 0.f;
  const float* hbase = hs + (size_t)b * T_ * H_;
  for (int t = 0; t < T_; ++t) {
    const float s = sw[t];
    a0 += s * hbase[(size_t)t * H_ + tid];
    a1 += s * hbase[(size_t)t * H_ + 256 + tid];
  }
  pooled[b * H_ + tid] = a0;
  pooled[b * H_ + 256 + tid] = a1;
}

// ---- final dense (H->3) ----------------------------------------------------
__global__ __launch_bounds__(64) void k_dense(const float* __restrict__ pooled, const float* __restrict__ dw,
                                              const float* __restrict__ db, float* __restrict__ out) {
  const int b = blockIdx.x, lane = threadIdx.x;
  float a0 = 0.f, a1 = 0.f, a2 = 0.f;
#pragma unroll
  for (int m = 0; m < 8; ++m) {
    int h = lane + m * 64;
    float pv = pooled[b * H_ + h];
    a0 += pv * dw[h * 3 + 0];
    a1 += pv * dw[h * 3 + 1];
    a2 += pv * dw[h * 3 + 2];
  }
#pragma unroll
  for (int off = 32; off > 0; off >>= 1) {
    a0 += __shfl_down(a0, off);
    a1 += __shfl_down(a1, off);
    a2 += __shfl_down(a2, off);
  }
  if (lane == 0) {
    out[b * 3 + 0] = a0 + db[0];
    out[b * 3 + 1] = a1 + db[1];
    out[b * 3 + 2] = a2 + db[2];
  }
}

extern "C" void kernel_launch(void* const* d_in, const int* in_sizes, int n_in,
                              void* d_out, int out_size, void* d_ws, size_t ws_size,
                              hipStream_t stream) {
  (void)in_sizes; (void)n_in; (void)out_size;
  const int*   tidx  = (const int*)d_in[0];
  const int*   aidx  = (const int*)d_in[1];
  const float* embed = (const float*)d_in[2];
  const float* w_ih  = (const float*)d_in[3];
  const float* w_hh  = (const float*)d_in[4];
  const float* b_gru = (const float*)d_in[5];
  const float* wk_w  = (const float*)d_in[6];
  // d_in[7] = wk_b: cancels in softmax, unused
  const float* wq_w  = (const float*)d_in[8];
  const float* wq_b  = (const float*)d_in[9];
  const float* q_p   = (const float*)d_in[10];
  const float* bil_w = (const float*)d_in[11];
  const float* dw    = (const float*)d_in[12];
  const float* db    = (const float*)d_in[13];
  float* out = (float*)d_out;

  // choose superchunk length by workspace capacity (deterministic: ws_size fixed)
  const size_t fixed_floats =
      (size_t)B_ * H_ * 2 * 2 +          // hA64 + hB64 (u64 as 2 floats)
      (size_t)G3_ * E_ / 2 * 2 +         // Bhg + Blg (u16 as half floats)
      (size_t)B_ * E_ + (size_t)B_ * G3_ + D_ + D_ + H_ +
      (size_t)B_ * T_ + (size_t)B_ * H_ +
      (size_t)G3_ * H_ + (size_t)B_ * T_ * H_;
  int TSC = 64, TSHIFT = 6;
  if ((fixed_floats + (size_t)B_ * 64 * G3_) * 4 > ws_size) { TSC = 16; TSHIFT = 4; }
  const int NSC = T_ / TSC;

  float* ws = (float*)d_ws;
  size_t off = 0;
  unsigned long long* hA64 = (unsigned long long*)(ws + off); off += (size_t)B_ * H_ * 2;
  unsigned long long* hB64 = (unsigned long long*)(ws + off); off += (size_t)B_ * H_ * 2;
  unsigned short* Bhg = (unsigned short*)(ws + off); off += (size_t)G3_ * E_ / 2;
  unsigned short* Blg = (unsigned short*)(ws + off); off += (size_t)G3_ * E_ / 2;
  float* ap     = ws + off; off += (size_t)B_ * E_;
  float* ag     = ws + off; off += (size_t)B_ * G3_;
  float* qx     = ws + off; off += D_;
  float* qw     = ws + off; off += D_;
  float* u      = ws + off; off += H_;
  float* lg     = ws + off; off += (size_t)B_ * T_;
  float* pooled = ws + off; off += (size_t)B_ * H_;
  float* whhT   = ws + off; off += (size_t)G3_ * H_;
  float* xgbuf  = ws + off; off += (size_t)B_ * TSC * G3_;
  float* hs     = ws + off; off += (size_t)B_ * T_ * H_;

  // zero both tagged h buffers: hA supplies {h=0, tag=0} for step 0; clean
  // tags every launch make graph replays independent of leftover state.
  hipMemsetAsync(hA64, 0, (size_t)B_ * H_ * 2 * sizeof(unsigned long long), stream);

  k_transpose<<<dim3(48, 16), 256, 0, stream>>>(w_hh, whhT);
  k_prep_bsplit<<<dim3(48, 16), 256, 0, stream>>>(w_ih, Bhg, Blg);
  k_asp_pool<<<B_, 256, 0, stream>>>(aidx, embed, ap);
  k_matvecT<<<4, 256, 0, stream>>>(q_p, wq_w, wq_b, qx, D_, D_);
  k_matvecT<<<4, 256, 0, stream>>>(qx, bil_w, nullptr, qw, D_, D_);
  k_u<<<128, 256, 0, stream>>>(wk_w, qw, u);
  k_ag<<<dim3(6, 32), 256, 0, stream>>>(ap, w_ih, b_gru, ag);

  for (int sc = 0; sc < NSC; ++sc) {
    k_gemm_xg_mfma<<<dim3(24, B_ * TSC / 64), 256, 0, stream>>>(
        tidx, embed, Bhg, Blg, ag, xgbuf, sc, TSC, TSHIFT);
    int scA = sc, tscA = TSC;
    void* args[] = { (void*)&whhT, (void*)&xgbuf, (void*)&hA64, (void*)&hB64,
                     (void*)&hs, (void*)&scA, (void*)&tscA };
    hipLaunchCooperativeKernel((const void*)k_gru_chunk, dim3(256), dim3(512),
                               args, 0, stream);
  }

  k_logits<<<8192, 256, 0, stream>>>(hs, u, lg);
  k_softmax_pool<<<B_, 256, 0, stream>>>(lg, hs, pooled);
  k_dense<<<B_, 64, 0, stream>>>(pooled, dw, db, out);
}